// Round 1
// baseline (267.464 us; speedup 1.0000x reference)
//
#include <hip/hip_runtime.h>

#define BB 8
#define SS 4096
#define DD 128

typedef __attribute__((ext_vector_type(8))) short v8s;
typedef __attribute__((ext_vector_type(4))) float v4f;

__device__ __forceinline__ unsigned short f2bf(float f) {
    unsigned int u = __float_as_uint(f);
    u += 0x7fffu + ((u >> 16) & 1u);
    return (unsigned short)(u >> 16);
}

// ---------------- kernel 0: W[k][n] fp32 -> Wt[w][n][k] bf16 ----------------
__global__ __launch_bounds__(256) void prep_w_kernel(
    const float* __restrict__ Wq, const float* __restrict__ Wk,
    const float* __restrict__ Wv, unsigned short* __restrict__ Wt)
{
    int id = blockIdx.x * 256 + threadIdx.x;   // grid = 192 blocks -> id < 49152
    int w = id >> 14;
    int n = (id >> 7) & 127;
    int k = id & 127;
    const float* W = (w == 0) ? Wq : (w == 1) ? Wk : Wv;
    Wt[id] = f2bf(W[k * 128 + n]);
}

// ---------------- kernel 1: xp = x + pe; q/k/v projections ----------------
// 512 blocks x 256 thr; each block does 64 flat rows; each wave 16 rows.
// q scaled by 1/sqrt(A). v written transposed: vT[b][a][s].
__global__ __launch_bounds__(256) void proj_kernel(
    const float* __restrict__ x, const unsigned short* __restrict__ Wt,
    const float* __restrict__ bq, const float* __restrict__ bk,
    const float* __restrict__ bv,
    unsigned short* __restrict__ qo, unsigned short* __restrict__ ko,
    unsigned short* __restrict__ vo)
{
    const int tid = threadIdx.x;
    const int wave = tid >> 6;
    const int lane = tid & 63;
    const int quad = lane >> 4;
    const int l15 = lane & 15;
    const int tile = blockIdx.x * 64;            // flat row base (b*S + s)
    const int flatrow = tile + wave * 16 + l15;  // A-frag row (m = lane&15)
    const int srow = flatrow & 4095;             // sequence position

    // Build A-frags: xp[m][k], m = l15, k = kc*32 + quad*8 + j
    v8s af[4];
#pragma unroll
    for (int kc = 0; kc < 4; ++kc) {
        const int kbase = kc * 32 + quad * 8;
        const v4f* xp = (const v4f*)(x + (size_t)flatrow * DD + kbase);
        v4f x0 = xp[0], x1 = xp[1];
        float xv[8] = {x0[0], x0[1], x0[2], x0[3], x1[0], x1[1], x1[2], x1[3]};
        v8s a;
#pragma unroll
        for (int j = 0; j < 8; ++j) {
            int d = kbase + j;
            // div = exp(-(ln 1e4)/128 * 2i), arg = s*div (all fp32, matches np)
            float freq = __expf((float)(d & ~1) * -0.07195578415606394f);
            float arg = (float)srow * freq;
            float pe = (d & 1) ? cosf(arg) : sinf(arg);
            a[j] = (short)f2bf(xv[j] + pe);
        }
        af[kc] = a;
    }

#pragma unroll
    for (int w = 0; w < 3; ++w) {
        const unsigned short* Wp = Wt + (w << 14);
        const float* bias = (w == 0) ? bq : (w == 1) ? bk : bv;
#pragma unroll
        for (int nb = 0; nb < 8; ++nb) {
            const int col = nb * 16 + l15;
            v4f acc = {0.f, 0.f, 0.f, 0.f};
#pragma unroll
            for (int kc = 0; kc < 4; ++kc) {
                v8s bf = *(const v8s*)(Wp + col * 128 + kc * 32 + quad * 8);
                acc = __builtin_amdgcn_mfma_f32_16x16x32_bf16(af[kc], bf, acc, 0, 0, 0);
            }
            float bval = bias[col];
#pragma unroll
            for (int reg = 0; reg < 4; ++reg) {
                int r = tile + wave * 16 + quad * 4 + reg;   // flat out row
                float val = acc[reg] + bval;
                if (w == 0) {
                    qo[(size_t)r * DD + col] = f2bf(val * 0.08838834764831845f);
                } else if (w == 1) {
                    ko[(size_t)r * DD + col] = f2bf(val);
                } else {
                    int bb = r >> 12, sr = r & 4095;
                    vo[((size_t)bb * DD + col) * SS + sr] = f2bf(val);
                }
            }
        }
    }
}

// ---------------- kernel 2: flash attention ----------------
#define KT 64           // key tile
#define KSTRIDE 136     // 128 + 8 bf16 pad: 16B-aligned rows, 2-way banks (free)
#define VSTRIDE 72      // 64 + 8
#define PSTRIDE 72      // 64 + 8

__global__ __launch_bounds__(256, 3) void flash_kernel(
    const unsigned short* __restrict__ qg,
    const unsigned short* __restrict__ kg,
    const unsigned short* __restrict__ vg,   // transposed [B][A][S]
    float* __restrict__ out)
{
    __shared__ __attribute__((aligned(16))) unsigned short k_lds[KT * KSTRIDE];   // 17408 B
    __shared__ __attribute__((aligned(16))) unsigned short v_lds[128 * VSTRIDE];  // 18432 B
    __shared__ __attribute__((aligned(16))) unsigned short p_lds[4 * 16 * PSTRIDE]; // 9216 B

    const int tid = threadIdx.x;
    const int wave = tid >> 6;
    const int lane = tid & 63;
    const int quad = lane >> 4;
    const int l15 = lane & 15;
    const int b = blockIdx.x & 7;     // batch -> XCD pinning heuristic
    const int qt = blockIdx.x >> 3;
    const int qbase = qt * 64;

    // Q frags resident in registers: q[m = l15][k = kc*32 + quad*8 + j]
    const size_t qrow = (size_t)(b * SS + qbase + wave * 16 + l15) * DD;
    v8s qf[4];
#pragma unroll
    for (int kc = 0; kc < 4; ++kc)
        qf[kc] = *(const v8s*)(qg + qrow + kc * 32 + quad * 8);

    v4f o[8];
#pragma unroll
    for (int i = 0; i < 8; ++i) o[i] = (v4f){0.f, 0.f, 0.f, 0.f};
    float m[4]     = {-1e30f, -1e30f, -1e30f, -1e30f};
    float lpart[4] = {0.f, 0.f, 0.f, 0.f};

    unsigned short* pw = p_lds + wave * 16 * PSTRIDE;
    const unsigned short* kb = kg + (size_t)b * SS * DD;
    const unsigned short* vb = vg + (size_t)b * DD * SS;

    for (int kt = 0; kt < SS / KT; ++kt) {
        __syncthreads();
        // stage K tile [64][128] and V^T tile [128][64] (coalesced 16B loads)
        {
            int r0 = tid >> 4, c8 = tid & 15;
#pragma unroll
            for (int c = 0; c < 4; ++c) {
                int r = r0 + c * 16;
                v8s val = *(const v8s*)(kb + (size_t)(kt * KT + r) * DD + c8 * 8);
                *(v8s*)(k_lds + r * KSTRIDE + c8 * 8) = val;
            }
            int a0 = tid >> 3, c8v = tid & 7;
#pragma unroll
            for (int c = 0; c < 4; ++c) {
                int a = a0 + c * 32;
                v8s val = *(const v8s*)(vb + (size_t)a * SS + kt * KT + c8v * 8);
                *(v8s*)(v_lds + a * VSTRIDE + c8v * 8) = val;
            }
        }
        __syncthreads();

        // S = q @ k^T   (rows: quad*4+reg, cols: nb*16+l15)
        v4f sacc[4];
#pragma unroll
        for (int nb = 0; nb < 4; ++nb) {
            v4f acc = {0.f, 0.f, 0.f, 0.f};
#pragma unroll
            for (int kc = 0; kc < 4; ++kc) {
                v8s bf = *(const v8s*)(k_lds + (nb * 16 + l15) * KSTRIDE + kc * 32 + quad * 8);
                acc = __builtin_amdgcn_mfma_f32_16x16x32_bf16(qf[kc], bf, acc, 0, 0, 0);
            }
            sacc[nb] = acc;
        }

        // online softmax (per-row stats; rows owned by 16-lane groups)
        float alpha[4];
#pragma unroll
        for (int reg = 0; reg < 4; ++reg) {
            float mx = fmaxf(fmaxf(sacc[0][reg], sacc[1][reg]),
                             fmaxf(sacc[2][reg], sacc[3][reg]));
#pragma unroll
            for (int sh = 1; sh < 16; sh <<= 1)
                mx = fmaxf(mx, __shfl_xor(mx, sh, 64));
            float mnew = fmaxf(m[reg], mx);
            alpha[reg] = __expf(m[reg] - mnew);
            m[reg] = mnew;
            float rs = 0.f;
#pragma unroll
            for (int nb = 0; nb < 4; ++nb) {
                float p = __expf(sacc[nb][reg] - mnew);
                sacc[nb][reg] = p;
                rs += p;
            }
            // deferred l: per-lane partial, reduced once at the end
            lpart[reg] = lpart[reg] * alpha[reg] + rs;
        }

        // write P (bf16) to this wave's private LDS block, A-layout friendly
#pragma unroll
        for (int reg = 0; reg < 4; ++reg) {
            int row = quad * 4 + reg;
#pragma unroll
            for (int nb = 0; nb < 4; ++nb)
                pw[row * PSTRIDE + nb * 16 + l15] = f2bf(sacc[nb][reg]);
        }

        // rescale O
#pragma unroll
        for (int ab = 0; ab < 8; ++ab)
#pragma unroll
            for (int reg = 0; reg < 4; ++reg)
                o[ab][reg] *= alpha[reg];

        // O += P @ V : A-frag P[m=l15][t], B-frag V[t][a] from v_lds^T
        v8s pa[2];
#pragma unroll
        for (int tc = 0; tc < 2; ++tc)
            pa[tc] = *(const v8s*)(pw + l15 * PSTRIDE + tc * 32 + quad * 8);
#pragma unroll
        for (int ab = 0; ab < 8; ++ab) {
#pragma unroll
            for (int tc = 0; tc < 2; ++tc) {
                v8s bf = *(const v8s*)(v_lds + (ab * 16 + l15) * VSTRIDE + tc * 32 + quad * 8);
                o[ab] = __builtin_amdgcn_mfma_f32_16x16x32_bf16(pa[tc], bf, o[ab], 0, 0, 0);
            }
        }
    }

    // epilogue: final l reduction + normalize + store
    float inv[4];
#pragma unroll
    for (int reg = 0; reg < 4; ++reg) {
        float l = lpart[reg];
#pragma unroll
        for (int sh = 1; sh < 16; sh <<= 1)
            l += __shfl_xor(l, sh, 64);
        inv[reg] = 1.0f / l;
    }
#pragma unroll
    for (int ab = 0; ab < 8; ++ab)
#pragma unroll
        for (int reg = 0; reg < 4; ++reg) {
            int sr = qbase + wave * 16 + quad * 4 + reg;
            out[(size_t)(b * SS + sr) * DD + ab * 16 + l15] = o[ab][reg] * inv[reg];
        }
}

extern "C" void kernel_launch(void* const* d_in, const int* in_sizes, int n_in,
                              void* d_out, int out_size, void* d_ws, size_t ws_size,
                              hipStream_t stream)
{
    const float* x  = (const float*)d_in[0];
    const float* Wq = (const float*)d_in[1];
    const float* bq = (const float*)d_in[2];
    const float* Wk = (const float*)d_in[3];
    const float* bk = (const float*)d_in[4];
    const float* Wv = (const float*)d_in[5];
    const float* bv = (const float*)d_in[6];
    float* out = (float*)d_out;

    unsigned short* Wt = (unsigned short*)d_ws;          // 3*128*128 bf16
    unsigned short* q  = Wt + 3 * 128 * 128;             // B*S*D bf16
    unsigned short* k  = q + (size_t)BB * SS * DD;
    unsigned short* vT = k + (size_t)BB * SS * DD;       // transposed [B][A][S]

    hipLaunchKernelGGL(prep_w_kernel, dim3(192), dim3(256), 0, stream, Wq, Wk, Wv, Wt);
    hipLaunchKernelGGL(proj_kernel, dim3(BB * SS / 64), dim3(256), 0, stream,
                       x, Wt, bq, bk, bv, q, k, vT);
    hipLaunchKernelGGL(flash_kernel, dim3(BB * SS / 64), dim3(256), 0, stream,
                       q, k, vT, out);
}